// Round 2
// baseline (1067.448 us; speedup 1.0000x reference)
//
#include <hip/hip_runtime.h>
#include <hip/hip_bf16.h>

typedef __attribute__((ext_vector_type(8))) short bf16x8;
typedef __attribute__((ext_vector_type(4))) float f32x4;

#define NH  16
#define HD  64
#define SEQ 2048
#define DM  1024   // NH*HD
#define NB  4

#define MFMA(a,b,c) __builtin_amdgcn_mfma_f32_16x16x32_bf16((a),(b),(c),0,0,0)

// ---------------- cast float -> bf16, 4 elems/thread ----------------
__global__ void cast_f32_bf16(const float* __restrict__ src,
                              __hip_bfloat16* __restrict__ dst, long n) {
    long i = ((long)blockIdx.x * blockDim.x + threadIdx.x) * 4;
    if (i >= n) return;
    float4 v = *reinterpret_cast<const float4*>(src + i);
    ushort4 o;
    o.x = __bfloat16_as_ushort(__float2bfloat16(v.x));
    o.y = __bfloat16_as_ushort(__float2bfloat16(v.y));
    o.z = __bfloat16_as_ushort(__float2bfloat16(v.z));
    o.w = __bfloat16_as_ushort(__float2bfloat16(v.w));
    *reinterpret_cast<ushort4*>(dst + i) = o;
}

// ------------- transpose+cast [mats][R][C] f32 -> [mats][C][R] bf16 -------------
__global__ void transpose_cast_k(const float* __restrict__ src,
                                 __hip_bfloat16* __restrict__ dst,
                                 int mats, int R, int C) {
    long idx = (long)blockIdx.x * blockDim.x + threadIdx.x;
    long total = (long)mats * R * C;
    if (idx >= total) return;
    int c = (int)(idx % C);
    long t = idx / C;
    int r = (int)(t % R);
    int m = (int)(t / R);
    dst[((long)m * C + c) * R + r] = __float2bfloat16(src[idx]);
}

// ---------------- QKV projection ----------------
// xb: [B*S=8192][1024] bf16; wt (transposed): [H][HD][D] bf16;
// out Q,K: [B,H,S,HD] bf16; V: [B,H,HD,S] bf16
__global__ __launch_bounds__(256)
void qkv_proj(const __hip_bfloat16* __restrict__ xb,
              const __hip_bfloat16* __restrict__ wqt,
              const __hip_bfloat16* __restrict__ wkt,
              const __hip_bfloat16* __restrict__ wvt,
              const float* __restrict__ bq,
              const float* __restrict__ bk,
              const float* __restrict__ bv,
              __hip_bfloat16* __restrict__ Qo,
              __hip_bfloat16* __restrict__ Ko,
              __hip_bfloat16* __restrict__ Vto) {
    int mt = blockIdx.x;          // 0..127 (64-row tiles of B*S)
    int h  = blockIdx.y;          // 0..15
    int z  = blockIdx.z;          // 0:q 1:k 2:v
    int tid = threadIdx.x;
    int w = tid >> 6, l = tid & 63;
    int lr = l & 15, lg = l >> 4;

    const __hip_bfloat16* wt   = (z == 0) ? wqt : (z == 1) ? wkt : wvt;
    const float*          bias = (z == 0) ? bq  : (z == 1) ? bk  : bv;

    const __hip_bfloat16* arow = xb + (long)(mt * 64 + w * 16 + lr) * DM;

    f32x4 acc[4] = {};
    for (int k0 = 0; k0 < DM; k0 += 32) {
        bf16x8 a = *reinterpret_cast<const bf16x8*>(arow + k0 + lg * 8);
#pragma unroll
        for (int n = 0; n < 4; ++n) {
            const __hip_bfloat16* bp2 =
                wt + ((long)h * HD + n * 16 + lr) * DM + k0 + lg * 8;
            bf16x8 b = *reinterpret_cast<const bf16x8*>(bp2);
            acc[n] = MFMA(a, b, acc[n]);
        }
    }

    int orow0 = mt * 64 + w * 16 + lg * 4;
#pragma unroll
    for (int n = 0; n < 4; ++n) {
        int e = n * 16 + lr;
        float bb = bias[h * HD + e];
#pragma unroll
        for (int r = 0; r < 4; ++r) {
            int row = orow0 + r;
            int b = row >> 11, s = row & 2047;
            float v = acc[n][r] + bb;
            if (z == 0) {
                Qo[(((long)b * NH + h) * SEQ + s) * HD + e] = __float2bfloat16(v);
            } else if (z == 1) {
                Ko[(((long)b * NH + h) * SEQ + s) * HD + e] = __float2bfloat16(v);
            } else {
                Vto[(((long)b * NH + h) * HD + e) * SEQ + s] = __float2bfloat16(v);
            }
        }
    }
}

// ---------------- flash attention (causal) ----------------
// Q,K: [B,H,S,HD]; Vt: [B,H,HD,S]; O: [B,H,S,HD]  (all bf16)
__global__ __launch_bounds__(256)
void flash_attn(const __hip_bfloat16* __restrict__ Q,
                const __hip_bfloat16* __restrict__ K,
                const __hip_bfloat16* __restrict__ Vt,
                __hip_bfloat16* __restrict__ O) {
    __shared__ __hip_bfloat16 Plds[4][16][32];
    int qt = blockIdx.x;          // 0..31 (64 q rows / block)
    int bh = blockIdx.y;          // 0..63
    int tid = threadIdx.x;
    int w = tid >> 6, l = tid & 63;
    int lr = l & 15, lg = l >> 4;

    const __hip_bfloat16* Qh = Q  + (long)bh * SEQ * HD;
    const __hip_bfloat16* Kh = K  + (long)bh * SEQ * HD;
    const __hip_bfloat16* Vh = Vt + (long)bh * HD * SEQ;   // [64][2048]

    int q0 = qt * 64 + w * 16;

    bf16x8 aq0 = *reinterpret_cast<const bf16x8*>(Qh + (long)(q0 + lr) * HD + lg * 8);
    bf16x8 aq1 = *reinterpret_cast<const bf16x8*>(Qh + (long)(q0 + lr) * HD + 32 + lg * 8);

    f32x4 o[4] = {};
    float mrun[4] = {-INFINITY, -INFINITY, -INFINITY, -INFINITY};
    float lsum[4] = {0.f, 0.f, 0.f, 0.f};

    int ntiles = (q0 + 16 + 31) >> 5;   // kv tiles of 32 covering kv <= q0+15
    for (int t = 0; t < ntiles; ++t) {
        int kv0 = t * 32;
        f32x4 s[2];
#pragma unroll
        for (int nk = 0; nk < 2; ++nk) {
            f32x4 sa = {0.f, 0.f, 0.f, 0.f};
            const __hip_bfloat16* krow =
                Kh + (long)(kv0 + nk * 16 + lr) * HD + lg * 8;
            bf16x8 b0 = *reinterpret_cast<const bf16x8*>(krow);
            bf16x8 b1 = *reinterpret_cast<const bf16x8*>(krow + 32);
            sa = MFMA(aq0, b0, sa);
            sa = MFMA(aq1, b1, sa);
            s[nk] = sa;
        }
        // scale + causal mask + row max (16-lane groups share a row-set)
        float mt_[4];
#pragma unroll
        for (int r = 0; r < 4; ++r) {
            int q = q0 + lg * 4 + r;
            float v0 = s[0][r] * 0.125f;
            float v1 = s[1][r] * 0.125f;
            v0 = (kv0 + lr      <= q) ? v0 : -INFINITY;
            v1 = (kv0 + 16 + lr <= q) ? v1 : -INFINITY;
            s[0][r] = v0; s[1][r] = v1;
            float mx = fmaxf(v0, v1);
            mx = fmaxf(mx, __shfl_xor(mx, 1));
            mx = fmaxf(mx, __shfl_xor(mx, 2));
            mx = fmaxf(mx, __shfl_xor(mx, 4));
            mx = fmaxf(mx, __shfl_xor(mx, 8));
            mt_[r] = mx;
        }
#pragma unroll
        for (int r = 0; r < 4; ++r) {
            float mnew = fmaxf(mrun[r], mt_[r]);
            float fac = __expf(mrun[r] - mnew);   // mrun=-inf,mnew finite -> 0
            lsum[r] *= fac;
            o[0][r] *= fac; o[1][r] *= fac; o[2][r] *= fac; o[3][r] *= fac;
            float p0 = __expf(s[0][r] - mnew);
            float p1 = __expf(s[1][r] - mnew);
            float ps = p0 + p1;
            ps += __shfl_xor(ps, 1);
            ps += __shfl_xor(ps, 2);
            ps += __shfl_xor(ps, 4);
            ps += __shfl_xor(ps, 8);
            lsum[r] += ps;
            mrun[r] = mnew;
            Plds[w][lg * 4 + r][lr]      = __float2bfloat16(p0);
            Plds[w][lg * 4 + r][16 + lr] = __float2bfloat16(p1);
        }
        asm volatile("s_waitcnt lgkmcnt(0)" ::: "memory");
        __builtin_amdgcn_sched_barrier(0);
        bf16x8 pa = *reinterpret_cast<const bf16x8*>(&Plds[w][lr][lg * 8]);
#pragma unroll
        for (int n = 0; n < 4; ++n) {
            const __hip_bfloat16* vrow =
                Vh + (long)(n * 16 + lr) * SEQ + kv0 + lg * 8;
            bf16x8 bv8 = *reinterpret_cast<const bf16x8*>(vrow);
            o[n] = MFMA(pa, bv8, o[n]);
        }
    }

#pragma unroll
    for (int r = 0; r < 4; ++r) {
        float inv = 1.0f / lsum[r];
        int qrow = q0 + lg * 4 + r;
#pragma unroll
        for (int n = 0; n < 4; ++n) {
            O[((long)bh * SEQ + qrow) * HD + n * 16 + lr] =
                __float2bfloat16(o[n][r] * inv);
        }
    }
}

// ---------------- output projection ----------------
// O: [B,H,S,HD] bf16 read as [8192][1024] (d' = h*64+e); Wpt: [1024][1024] bf16 (Wp^T);
// out: [B,S,1024] float32
__global__ __launch_bounds__(256)
void out_proj(const __hip_bfloat16* __restrict__ O,
              const __hip_bfloat16* __restrict__ Wpt,
              const float* __restrict__ bp,
              float* __restrict__ out) {
    int mt = blockIdx.x;   // 0..127
    int nt = blockIdx.y;   // 0..15
    int tid = threadIdx.x;
    int w = tid >> 6, l = tid & 63;
    int lr = l & 15, lg = l >> 4;

    int row = mt * 64 + w * 16 + lr;
    int b = row >> 11, s = row & 2047;

    f32x4 acc[4] = {};
    for (int k0 = 0; k0 < DM; k0 += 32) {
        int kk = k0 + lg * 8;
        int h = kk >> 6, e = kk & 63;
        bf16x8 a = *reinterpret_cast<const bf16x8*>(
            O + (((long)b * NH + h) * SEQ + s) * HD + e);
#pragma unroll
        for (int n = 0; n < 4; ++n) {
            bf16x8 bf = *reinterpret_cast<const bf16x8*>(
                Wpt + (long)(nt * 64 + n * 16 + lr) * DM + kk);
            acc[n] = MFMA(a, bf, acc[n]);
        }
    }

    int orow0 = mt * 64 + w * 16 + lg * 4;
#pragma unroll
    for (int n = 0; n < 4; ++n) {
        int col = nt * 64 + n * 16 + lr;
        float bb = bp[col];
#pragma unroll
        for (int r = 0; r < 4; ++r) {
            out[(long)(orow0 + r) * DM + col] = acc[n][r] + bb;
        }
    }
}

extern "C" void kernel_launch(void* const* d_in, const int* in_sizes, int n_in,
                              void* d_out, int out_size, void* d_ws, size_t ws_size,
                              hipStream_t stream) {
    const float* x  = (const float*)d_in[0];
    const float* Wq = (const float*)d_in[1];
    const float* bq = (const float*)d_in[2];
    const float* Wk = (const float*)d_in[3];
    const float* bk = (const float*)d_in[4];
    const float* Wv = (const float*)d_in[5];
    const float* bv = (const float*)d_in[6];
    const float* Wp = (const float*)d_in[7];
    const float* bp = (const float*)d_in[8];
    float* out = (float*)d_out;

    char* ws = (char*)d_ws;
    const long XE = (long)NB * SEQ * DM;                 // 8,388,608
    const long QKV_ELEMS = (long)NB * NH * SEQ * HD;     // 8,388,608
    __hip_bfloat16* xb   = (__hip_bfloat16*)ws; ws += XE * 2;
    __hip_bfloat16* Qws  = (__hip_bfloat16*)ws; ws += QKV_ELEMS * 2;
    __hip_bfloat16* Kws  = (__hip_bfloat16*)ws; ws += QKV_ELEMS * 2;
    __hip_bfloat16* Vtws = (__hip_bfloat16*)ws; ws += QKV_ELEMS * 2;
    __hip_bfloat16* Ows  = (__hip_bfloat16*)ws; ws += QKV_ELEMS * 2;
    __hip_bfloat16* wqt  = (__hip_bfloat16*)ws; ws += (long)NH * DM * HD * 2;
    __hip_bfloat16* wkt  = (__hip_bfloat16*)ws; ws += (long)NH * DM * HD * 2;
    __hip_bfloat16* wvt  = (__hip_bfloat16*)ws; ws += (long)NH * DM * HD * 2;
    __hip_bfloat16* wpt  = (__hip_bfloat16*)ws; ws += (long)DM * DM * 2;

    cast_f32_bf16<<<(int)(XE / 4 / 256), 256, 0, stream>>>(x, xb, XE);

    {
        long tot = (long)NH * DM * HD;
        int blks = (int)((tot + 255) / 256);
        transpose_cast_k<<<blks, 256, 0, stream>>>(Wq, wqt, NH, DM, HD);
        transpose_cast_k<<<blks, 256, 0, stream>>>(Wk, wkt, NH, DM, HD);
        transpose_cast_k<<<blks, 256, 0, stream>>>(Wv, wvt, NH, DM, HD);
        long tot2 = (long)DM * DM;
        transpose_cast_k<<<(int)((tot2 + 255) / 256), 256, 0, stream>>>(Wp, wpt, 1, DM, DM);
    }

    qkv_proj<<<dim3(128, 16, 3), 256, 0, stream>>>(
        xb, wqt, wkt, wvt, bq, bk, bv, Qws, Kws, Vtws);

    flash_attn<<<dim3(32, 64), 256, 0, stream>>>(Qws, Kws, Vtws, Ows);

    out_proj<<<dim3(128, 16), 256, 0, stream>>>(Ows, wpt, bp, out);
}

// Round 3
// 873.682 us; speedup vs baseline: 1.2218x; 1.2218x over previous
//
#include <hip/hip_runtime.h>
#include <hip/hip_bf16.h>

typedef __attribute__((ext_vector_type(8)))  short bf16x8;
typedef __attribute__((ext_vector_type(4)))  float f32x4;
typedef __attribute__((ext_vector_type(16))) float f32x16;

#define NH  16
#define HD  64
#define SEQ 2048
#define DM  1024   // NH*HD
#define NB  4

#define MFMA(a,b,c)   __builtin_amdgcn_mfma_f32_16x16x32_bf16((a),(b),(c),0,0,0)
#define MFMA32(a,b,c) __builtin_amdgcn_mfma_f32_32x32x16_bf16((a),(b),(c),0,0,0)

// ---------------- cast float -> bf16, 4 elems/thread ----------------
__global__ void cast_f32_bf16(const float* __restrict__ src,
                              __hip_bfloat16* __restrict__ dst, long n) {
    long i = ((long)blockIdx.x * blockDim.x + threadIdx.x) * 4;
    if (i >= n) return;
    float4 v = *reinterpret_cast<const float4*>(src + i);
    ushort4 o;
    o.x = __bfloat16_as_ushort(__float2bfloat16(v.x));
    o.y = __bfloat16_as_ushort(__float2bfloat16(v.y));
    o.z = __bfloat16_as_ushort(__float2bfloat16(v.z));
    o.w = __bfloat16_as_ushort(__float2bfloat16(v.w));
    *reinterpret_cast<ushort4*>(dst + i) = o;
}

// ------------- transpose+cast [mats][R][C] f32 -> [mats][C][R] bf16 -------------
__global__ void transpose_cast_k(const float* __restrict__ src,
                                 __hip_bfloat16* __restrict__ dst,
                                 int mats, int R, int C) {
    long idx = (long)blockIdx.x * blockDim.x + threadIdx.x;
    long total = (long)mats * R * C;
    if (idx >= total) return;
    int c = (int)(idx % C);
    long t = idx / C;
    int r = (int)(t % R);
    int m = (int)(t / R);
    dst[((long)m * C + c) * R + r] = __float2bfloat16(src[idx]);
}

// ---------------- QKV projection ----------------
// xb: [B*S=8192][1024] bf16; wt (transposed): [H][HD][D] bf16;
// out Q (pre-scaled by 1/8), K: [B,H,S,HD] bf16; V: [B,H,HD,S] bf16
__global__ __launch_bounds__(256)
void qkv_proj(const __hip_bfloat16* __restrict__ xb,
              const __hip_bfloat16* __restrict__ wqt,
              const __hip_bfloat16* __restrict__ wkt,
              const __hip_bfloat16* __restrict__ wvt,
              const float* __restrict__ bq,
              const float* __restrict__ bk,
              const float* __restrict__ bv,
              __hip_bfloat16* __restrict__ Qo,
              __hip_bfloat16* __restrict__ Ko,
              __hip_bfloat16* __restrict__ Vto) {
    int mt = blockIdx.x;          // 0..127 (64-row tiles of B*S)
    int h  = blockIdx.y;          // 0..15
    int z  = blockIdx.z;          // 0:q 1:k 2:v
    int tid = threadIdx.x;
    int w = tid >> 6, l = tid & 63;
    int lr = l & 15, lg = l >> 4;

    const __hip_bfloat16* wt   = (z == 0) ? wqt : (z == 1) ? wkt : wvt;
    const float*          bias = (z == 0) ? bq  : (z == 1) ? bk  : bv;

    const __hip_bfloat16* arow = xb + (long)(mt * 64 + w * 16 + lr) * DM;

    f32x4 acc[4] = {};
    for (int k0 = 0; k0 < DM; k0 += 32) {
        bf16x8 a = *reinterpret_cast<const bf16x8*>(arow + k0 + lg * 8);
#pragma unroll
        for (int n = 0; n < 4; ++n) {
            const __hip_bfloat16* bp2 =
                wt + ((long)h * HD + n * 16 + lr) * DM + k0 + lg * 8;
            bf16x8 b = *reinterpret_cast<const bf16x8*>(bp2);
            acc[n] = MFMA(a, b, acc[n]);
        }
    }

    int orow0 = mt * 64 + w * 16 + lg * 4;
#pragma unroll
    for (int n = 0; n < 4; ++n) {
        int e = n * 16 + lr;
        float bb = bias[h * HD + e];
#pragma unroll
        for (int r = 0; r < 4; ++r) {
            int row = orow0 + r;
            int b = row >> 11, s = row & 2047;
            float v = acc[n][r] + bb;
            if (z == 0) {
                Qo[(((long)b * NH + h) * SEQ + s) * HD + e] =
                    __float2bfloat16(v * 0.125f);   // fold 1/sqrt(HD) into Q
            } else if (z == 1) {
                Ko[(((long)b * NH + h) * SEQ + s) * HD + e] = __float2bfloat16(v);
            } else {
                Vto[(((long)b * NH + h) * HD + e) * SEQ + s] = __float2bfloat16(v);
            }
        }
    }
}

// ---------------- helpers for flash ----------------
static __device__ __forceinline__ unsigned pkbf(float a, float b) {
    __hip_bfloat162 h = __float22bfloat162_rn(float2{a, b});  // a -> low 16
    union { __hip_bfloat162 h2; unsigned u; } u_; u_.h2 = h;
    return u_.u;
}
static __device__ __forceinline__ bf16x8 make_pb(unsigned w0, unsigned w1,
                                                 unsigned w2, unsigned w3) {
    union { unsigned u[4]; bf16x8 v; } u_;
    u_.u[0] = w0; u_.u[1] = w1; u_.u[2] = w2; u_.u[3] = w3;
    return u_.v;
}

// ---------------- flash attention (causal, swapped-QK^T 32x32) ----------------
// Q (pre-scaled), K: [B,H,S,HD]; Vt: [B,H,HD,S]; O: [B,H,S,HD]  (all bf16)
// One wave per 32 q-rows. No LDS. S^T = mfma32(Kfrag, Qfrag): lane holds 16
// scores of q-row (l&31); rows kv_local = (r&3)+8*(r>>2)+4*(l>>5).
__global__ __launch_bounds__(256)
void flash_attn(const __hip_bfloat16* __restrict__ Q,
                const __hip_bfloat16* __restrict__ K,
                const __hip_bfloat16* __restrict__ Vt,
                __hip_bfloat16* __restrict__ O) {
    int bh = blockIdx.y;
    int w  = threadIdx.x >> 6, l = threadIdx.x & 63;
    int lo5 = l & 31, hi = l >> 5;
    int qtile = 63 - (blockIdx.x * 4 + w);   // heavy tiles dispatched first
    int q0 = qtile * 32;

    const __hip_bfloat16* Qh = Q  + (long)bh * SEQ * HD;
    const __hip_bfloat16* Kh = K  + (long)bh * SEQ * HD;
    const __hip_bfloat16* Vh = Vt + (long)bh * HD * SEQ;   // [64][2048]
    __hip_bfloat16*       Oh = O  + (long)bh * SEQ * HD;

    // Q fragments (B-operand): lane holds Q[q0+lo5][kd*16 + hi*8 + j]
    bf16x8 qf[4];
#pragma unroll
    for (int kd = 0; kd < 4; ++kd)
        qf[kd] = *reinterpret_cast<const bf16x8*>(
            Qh + (long)(q0 + lo5) * HD + kd * 16 + hi * 8);

    f32x16 o0 = {}, o1 = {};
    float m = -INFINITY, lsum = 0.f;

    for (int t = 0; t <= qtile; ++t) {
        int kv0 = t * 32;
        // QK^T: S^T[kv][q]
        f32x16 st = {};
#pragma unroll
        for (int kd = 0; kd < 4; ++kd) {
            bf16x8 kf = *reinterpret_cast<const bf16x8*>(
                Kh + (long)(kv0 + lo5) * HD + kd * 16 + hi * 8);
            st = MFMA32(kf, qf[kd], st);
        }
        if (t == qtile) {   // diagonal tile: causal mask (kv_local > lo5)
#pragma unroll
            for (int r = 0; r < 16; ++r) {
                int kvloc = (r & 3) + 8 * (r >> 2) + 4 * hi;
                st[r] = (kvloc > lo5) ? -INFINITY : st[r];
            }
        }
        // row max (15 local + 1 cross-half)
        float tm = st[0];
#pragma unroll
        for (int r = 1; r < 16; ++r) tm = fmaxf(tm, st[r]);
        tm = fmaxf(tm, __shfl_xor(tm, 32));
        float mnew = fmaxf(m, tm);
        float fac = __expf(m - mnew);

        float p[16];
        float ls = 0.f;
#pragma unroll
        for (int r = 0; r < 16; ++r) {
            p[r] = __expf(st[r] - mnew);
            ls += p[r];
        }
        ls += __shfl_xor(ls, 32);
        lsum = lsum * fac + ls;
#pragma unroll
        for (int r = 0; r < 16; ++r) { o0[r] *= fac; o1[r] *= fac; }
        m = mnew;

        // P -> bf16 B-fragments (kv = ks*16 + hi*8 + j at lane)
        unsigned pk0 = pkbf(p[0],  p[1]),  pk1 = pkbf(p[2],  p[3]);
        unsigned pk2 = pkbf(p[4],  p[5]),  pk3 = pkbf(p[6],  p[7]);
        unsigned pk4 = pkbf(p[8],  p[9]),  pk5 = pkbf(p[10], p[11]);
        unsigned pk6 = pkbf(p[12], p[13]), pk7 = pkbf(p[14], p[15]);
        unsigned r0 = (unsigned)__shfl_xor((int)(hi ? pk0 : pk2), 32);
        unsigned r1 = (unsigned)__shfl_xor((int)(hi ? pk1 : pk3), 32);
        unsigned r2 = (unsigned)__shfl_xor((int)(hi ? pk4 : pk6), 32);
        unsigned r3 = (unsigned)__shfl_xor((int)(hi ? pk5 : pk7), 32);
        bf16x8 pb0 = make_pb(hi ? r0 : pk0, hi ? r1 : pk1,
                             hi ? pk2 : r0, hi ? pk3 : r1);
        bf16x8 pb1 = make_pb(hi ? r2 : pk4, hi ? r3 : pk5,
                             hi ? pk6 : r2, hi ? pk7 : r3);

        // PV: O^T[d][q] += V^T[d][kv] * P^T[kv][q]
#pragma unroll
        for (int ks = 0; ks < 2; ++ks) {
            bf16x8 pb = ks ? pb1 : pb0;
            bf16x8 v0 = *reinterpret_cast<const bf16x8*>(
                Vh + (long)(lo5) * SEQ + kv0 + ks * 16 + hi * 8);
            bf16x8 v1 = *reinterpret_cast<const bf16x8*>(
                Vh + (long)(32 + lo5) * SEQ + kv0 + ks * 16 + hi * 8);
            o0 = MFMA32(v0, pb, o0);
            o1 = MFMA32(v1, pb, o1);
        }
    }

    float inv = 1.0f / lsum;
    __hip_bfloat16* orow = Oh + (long)(q0 + lo5) * HD;
#pragma unroll
    for (int nd = 0; nd < 2; ++nd) {
#pragma unroll
        for (int rg = 0; rg < 4; ++rg) {
            ushort4 s4;
            float a0 = (nd ? o1[rg * 4 + 0] : o0[rg * 4 + 0]) * inv;
            float a1 = (nd ? o1[rg * 4 + 1] : o0[rg * 4 + 1]) * inv;
            float a2 = (nd ? o1[rg * 4 + 2] : o0[rg * 4 + 2]) * inv;
            float a3 = (nd ? o1[rg * 4 + 3] : o0[rg * 4 + 3]) * inv;
            s4.x = __bfloat16_as_ushort(__float2bfloat16(a0));
            s4.y = __bfloat16_as_ushort(__float2bfloat16(a1));
            s4.z = __bfloat16_as_ushort(__float2bfloat16(a2));
            s4.w = __bfloat16_as_ushort(__float2bfloat16(a3));
            int dbase = nd * 32 + rg * 8 + hi * 4;
            *reinterpret_cast<ushort4*>(orow + dbase) = s4;
        }
    }
}

// ---------------- output projection ----------------
// O: [B,H,S,HD] bf16 read as [8192][1024] (d' = h*64+e); Wpt: [1024][1024] bf16 (Wp^T);
// out: [B,S,1024] float32
__global__ __launch_bounds__(256)
void out_proj(const __hip_bfloat16* __restrict__ O,
              const __hip_bfloat16* __restrict__ Wpt,
              const float* __restrict__ bp,
              float* __restrict__ out) {
    int mt = blockIdx.x;   // 0..127
    int nt = blockIdx.y;   // 0..15
    int tid = threadIdx.x;
    int w = tid >> 6, l = tid & 63;
    int lr = l & 15, lg = l >> 4;

    int row = mt * 64 + w * 16 + lr;
    int b = row >> 11, s = row & 2047;

    f32x4 acc[4] = {};
    for (int k0 = 0; k0 < DM; k0 += 32) {
        int kk = k0 + lg * 8;
        int h = kk >> 6, e = kk & 63;
        bf16x8 a = *reinterpret_cast<const bf16x8*>(
            O + (((long)b * NH + h) * SEQ + s) * HD + e);
#pragma unroll
        for (int n = 0; n < 4; ++n) {
            bf16x8 bf = *reinterpret_cast<const bf16x8*>(
                Wpt + (long)(nt * 64 + n * 16 + lr) * DM + kk);
            acc[n] = MFMA(a, bf, acc[n]);
        }
    }

    int orow0 = mt * 64 + w * 16 + lg * 4;
#pragma unroll
    for (int n = 0; n < 4; ++n) {
        int col = nt * 64 + n * 16 + lr;
        float bb = bp[col];
#pragma unroll
        for (int r = 0; r < 4; ++r) {
            out[(long)(orow0 + r) * DM + col] = acc[n][r] + bb;
        }
    }
}

extern "C" void kernel_launch(void* const* d_in, const int* in_sizes, int n_in,
                              void* d_out, int out_size, void* d_ws, size_t ws_size,
                              hipStream_t stream) {
    const float* x  = (const float*)d_in[0];
    const float* Wq = (const float*)d_in[1];
    const float* bq = (const float*)d_in[2];
    const float* Wk = (const float*)d_in[3];
    const float* bk = (const float*)d_in[4];
    const float* Wv = (const float*)d_in[5];
    const float* bv = (const float*)d_in[6];
    const float* Wp = (const float*)d_in[7];
    const float* bp = (const float*)d_in[8];
    float* out = (float*)d_out;

    char* ws = (char*)d_ws;
    const long XE = (long)NB * SEQ * DM;                 // 8,388,608
    const long QKV_ELEMS = (long)NB * NH * SEQ * HD;     // 8,388,608
    __hip_bfloat16* xb   = (__hip_bfloat16*)ws; ws += XE * 2;
    __hip_bfloat16* Qws  = (__hip_bfloat16*)ws; ws += QKV_ELEMS * 2;
    __hip_bfloat16* Kws  = (__hip_bfloat16*)ws; ws += QKV_ELEMS * 2;
    __hip_bfloat16* Vtws = (__hip_bfloat16*)ws; ws += QKV_ELEMS * 2;
    __hip_bfloat16* Ows  = (__hip_bfloat16*)ws; ws += QKV_ELEMS * 2;
    __hip_bfloat16* wqt  = (__hip_bfloat16*)ws; ws += (long)NH * DM * HD * 2;
    __hip_bfloat16* wkt  = (__hip_bfloat16*)ws; ws += (long)NH * DM * HD * 2;
    __hip_bfloat16* wvt  = (__hip_bfloat16*)ws; ws += (long)NH * DM * HD * 2;
    __hip_bfloat16* wpt  = (__hip_bfloat16*)ws; ws += (long)DM * DM * 2;

    cast_f32_bf16<<<(int)(XE / 4 / 256), 256, 0, stream>>>(x, xb, XE);

    {
        long tot = (long)NH * DM * HD;
        int blks = (int)((tot + 255) / 256);
        transpose_cast_k<<<blks, 256, 0, stream>>>(Wq, wqt, NH, DM, HD);
        transpose_cast_k<<<blks, 256, 0, stream>>>(Wk, wkt, NH, DM, HD);
        transpose_cast_k<<<blks, 256, 0, stream>>>(Wv, wvt, NH, DM, HD);
        long tot2 = (long)DM * DM;
        transpose_cast_k<<<(int)((tot2 + 255) / 256), 256, 0, stream>>>(Wp, wpt, 1, DM, DM);
    }

    qkv_proj<<<dim3(128, 16, 3), 256, 0, stream>>>(
        xb, wqt, wkt, wvt, bq, bk, bv, Qws, Kws, Vtws);

    flash_attn<<<dim3(16, 64), 256, 0, stream>>>(Qws, Kws, Vtws, Ows);

    out_proj<<<dim3(128, 16), 256, 0, stream>>>(Ows, wpt, bp, out);
}

// Round 4
// 400.273 us; speedup vs baseline: 2.6668x; 2.1827x over previous
//
#include <hip/hip_runtime.h>
#include <hip/hip_bf16.h>

typedef __attribute__((ext_vector_type(8)))  short bf16x8;
typedef __attribute__((ext_vector_type(4)))  float f32x4;
typedef __attribute__((ext_vector_type(16))) float f32x16;

#define NH  16
#define HD  64
#define SEQ 2048
#define DM  1024   // NH*HD
#define NB  4

#define MFMA(a,b,c)   __builtin_amdgcn_mfma_f32_16x16x32_bf16((a),(b),(c),0,0,0)
#define MFMA32(a,b,c) __builtin_amdgcn_mfma_f32_32x32x16_bf16((a),(b),(c),0,0,0)

static __device__ __forceinline__ void gload_lds16(const void* g, void* l) {
    __builtin_amdgcn_global_load_lds(
        (const __attribute__((address_space(1))) void*)g,
        (__attribute__((address_space(3))) void*)l, 16, 0, 0);
}

// ---------------- cast float -> bf16, 4 elems/thread ----------------
__global__ void cast_f32_bf16(const float* __restrict__ src,
                              __hip_bfloat16* __restrict__ dst, long n) {
    long i = ((long)blockIdx.x * blockDim.x + threadIdx.x) * 4;
    if (i >= n) return;
    float4 v = *reinterpret_cast<const float4*>(src + i);
    ushort4 o;
    o.x = __bfloat16_as_ushort(__float2bfloat16(v.x));
    o.y = __bfloat16_as_ushort(__float2bfloat16(v.y));
    o.z = __bfloat16_as_ushort(__float2bfloat16(v.z));
    o.w = __bfloat16_as_ushort(__float2bfloat16(v.w));
    *reinterpret_cast<ushort4*>(dst + i) = o;
}

// ------------- transpose+cast [mats][R][C] f32 -> [mats][C][R] bf16 -------------
__global__ void transpose_cast_k(const float* __restrict__ src,
                                 __hip_bfloat16* __restrict__ dst,
                                 int mats, int R, int C) {
    long idx = (long)blockIdx.x * blockDim.x + threadIdx.x;
    long total = (long)mats * R * C;
    if (idx >= total) return;
    int c = (int)(idx % C);
    long t = idx / C;
    int r = (int)(t % R);
    int m = (int)(t / R);
    dst[((long)m * C + c) * R + r] = __float2bfloat16(src[idx]);
}

// ---------------- tiled GEMM: C[M][N] = A[M][1024] * BT[N][1024]^T ----------------
// 128x128 tile, BK=32, double-buffered LDS staged via global_load_lds(16B),
// XOR-swizzled (granule ^= (row>>1)&3) on both source and ds_read side.
// MODE 0: qkv epilogue (N=3072 fused; z=col>>10 selects Q/K/V layout+bias, Q*=0.125)
// MODE 1: float-out epilogue with bias (out projection)
template<int MODE>
__global__ __launch_bounds__(256)
void gemm_bt(const __hip_bfloat16* __restrict__ A,
             const __hip_bfloat16* __restrict__ BT,
             const float* __restrict__ b0,
             const float* __restrict__ b1,
             const float* __restrict__ b2,
             __hip_bfloat16* __restrict__ Qo,
             __hip_bfloat16* __restrict__ Ko,
             __hip_bfloat16* __restrict__ Vto,
             float* __restrict__ Fo) {
    __shared__ __align__(16) char smem[2][16384];   // [buf][A:0..8191 | B:8192..16383]
    int tid = threadIdx.x;
    int w = tid >> 6, l = tid & 63;
    int wr = w >> 1, wc = w & 1;
    int lr = l & 15, lg = l >> 4;
    int mtile = blockIdx.x, ntile = blockIdx.y;

    const __hip_bfloat16* Ab = A  + (long)mtile * 128 * DM;
    const __hip_bfloat16* Bb = BT + (long)ntile * 128 * DM;

    // staging: issue i covers rows i*64 + tid/4, granule (tid&3), src-swizzled
    const int srow0 = tid >> 2;
    const int srow1 = 64 + srow0;
    const int g0 = (tid & 3) ^ ((srow0 >> 1) & 3);   // same for srow1 (row+64)

    // ds_read byte offsets (per fragment), swizzle-matched
    int aoff[4], boff[4];
#pragma unroll
    for (int m = 0; m < 4; ++m) {
        int ra = wr * 64 + m * 16 + lr;
        aoff[m] = ra * 64 + ((lg ^ ((ra >> 1) & 3)) * 16);
        int rb = wc * 64 + m * 16 + lr;
        boff[m] = 8192 + rb * 64 + ((lg ^ ((rb >> 1) & 3)) * 16);
    }

    f32x4 acc[4][4] = {};

    // prologue stage
    {
        char* base = smem[0] + w * 1024;
        gload_lds16(Ab + (long)srow0 * DM + g0 * 8, base);
        gload_lds16(Ab + (long)srow1 * DM + g0 * 8, base + 4096);
        gload_lds16(Bb + (long)srow0 * DM + g0 * 8, base + 8192);
        gload_lds16(Bb + (long)srow1 * DM + g0 * 8, base + 12288);
    }
    __syncthreads();

    int cur = 0;
    for (int kt = 0; kt < 32; ++kt) {
        if (kt != 31) {
            int k0 = (kt + 1) * 32;
            char* base = smem[cur ^ 1] + w * 1024;
            gload_lds16(Ab + (long)srow0 * DM + k0 + g0 * 8, base);
            gload_lds16(Ab + (long)srow1 * DM + k0 + g0 * 8, base + 4096);
            gload_lds16(Bb + (long)srow0 * DM + k0 + g0 * 8, base + 8192);
            gload_lds16(Bb + (long)srow1 * DM + k0 + g0 * 8, base + 12288);
        }
        bf16x8 af[4], bf[4];
#pragma unroll
        for (int m = 0; m < 4; ++m)
            af[m] = *reinterpret_cast<const bf16x8*>(smem[cur] + aoff[m]);
#pragma unroll
        for (int n = 0; n < 4; ++n)
            bf[n] = *reinterpret_cast<const bf16x8*>(smem[cur] + boff[n]);
#pragma unroll
        for (int m = 0; m < 4; ++m)
#pragma unroll
            for (int n = 0; n < 4; ++n)
                acc[m][n] = MFMA(af[m], bf[n], acc[m][n]);
        __syncthreads();
        cur ^= 1;
    }

    if (MODE == 0) {
        int z = (ntile * 128) >> 10;                      // uniform per block
        const float* bias = (z == 0) ? b0 : (z == 1) ? b1 : b2;
        int colbase = (ntile * 128 + wc * 64) & 1023;
#pragma unroll
        for (int n = 0; n < 4; ++n) {
            int hc = colbase + n * 16 + lr;               // h*64+e
            int h = hc >> 6, e = hc & 63;
            float bb = bias[hc];
#pragma unroll
            for (int m = 0; m < 4; ++m) {
                int row0 = mtile * 128 + wr * 64 + m * 16 + lg * 4;
                int b = row0 >> 11, s0 = row0 & 2047;
                if (z == 0) {
#pragma unroll
                    for (int r = 0; r < 4; ++r)
                        Qo[(((long)b * NH + h) * SEQ + s0 + r) * HD + e] =
                            __float2bfloat16((acc[m][n][r] + bb) * 0.125f);
                } else if (z == 1) {
#pragma unroll
                    for (int r = 0; r < 4; ++r)
                        Ko[(((long)b * NH + h) * SEQ + s0 + r) * HD + e] =
                            __float2bfloat16(acc[m][n][r] + bb);
                } else {
                    ushort4 s4;
                    s4.x = __bfloat16_as_ushort(__float2bfloat16(acc[m][n][0] + bb));
                    s4.y = __bfloat16_as_ushort(__float2bfloat16(acc[m][n][1] + bb));
                    s4.z = __bfloat16_as_ushort(__float2bfloat16(acc[m][n][2] + bb));
                    s4.w = __bfloat16_as_ushort(__float2bfloat16(acc[m][n][3] + bb));
                    *reinterpret_cast<ushort4*>(
                        Vto + ((long)(b * NH + h) * HD + e) * SEQ + s0) = s4;
                }
            }
        }
    } else {
#pragma unroll
        for (int n = 0; n < 4; ++n) {
            int col = ntile * 128 + wc * 64 + n * 16 + lr;
            float bb = b0[col];
#pragma unroll
            for (int m = 0; m < 4; ++m) {
                long row0 = mtile * 128 + wr * 64 + m * 16 + lg * 4;
#pragma unroll
                for (int r = 0; r < 4; ++r)
                    Fo[(row0 + r) * DM + col] = acc[m][n][r] + bb;
            }
        }
    }
}

// ---------------- helpers for flash ----------------
static __device__ __forceinline__ unsigned pkbf(float a, float b) {
    __hip_bfloat162 h = __float22bfloat162_rn(float2{a, b});  // a -> low 16
    union { __hip_bfloat162 h2; unsigned u; } u_; u_.h2 = h;
    return u_.u;
}
static __device__ __forceinline__ bf16x8 make_pb(unsigned w0, unsigned w1,
                                                 unsigned w2, unsigned w3) {
    union { unsigned u[4]; bf16x8 v; } u_;
    u_.u[0] = w0; u_.u[1] = w1; u_.u[2] = w2; u_.u[3] = w3;
    return u_.v;
}

// ---------------- flash attention (causal, swapped-QK^T 32x32) ----------------
// Q (pre-scaled), K: [B,H,S,HD]; Vt: [B,H,HD,S]; O: [B*S][DM] row-major (col h*64+d)
__global__ __launch_bounds__(256)
void flash_attn(const __hip_bfloat16* __restrict__ Q,
                const __hip_bfloat16* __restrict__ K,
                const __hip_bfloat16* __restrict__ Vt,
                __hip_bfloat16* __restrict__ O) {
    int bh = blockIdx.y;
    int w  = threadIdx.x >> 6, l = threadIdx.x & 63;
    int lo5 = l & 31, hi = l >> 5;
    int qtile = 63 - (blockIdx.x * 4 + w);   // heavy tiles dispatched first
    int q0 = qtile * 32;

    const __hip_bfloat16* Qh = Q  + (long)bh * SEQ * HD;
    const __hip_bfloat16* Kh = K  + (long)bh * SEQ * HD;
    const __hip_bfloat16* Vh = Vt + (long)bh * HD * SEQ;   // [64][2048]

    bf16x8 qf[4];
#pragma unroll
    for (int kd = 0; kd < 4; ++kd)
        qf[kd] = *reinterpret_cast<const bf16x8*>(
            Qh + (long)(q0 + lo5) * HD + kd * 16 + hi * 8);

    f32x16 o0 = {}, o1 = {};
    float m = -INFINITY, lsum = 0.f;

    for (int t = 0; t <= qtile; ++t) {
        int kv0 = t * 32;
        f32x16 st = {};
#pragma unroll
        for (int kd = 0; kd < 4; ++kd) {
            bf16x8 kf = *reinterpret_cast<const bf16x8*>(
                Kh + (long)(kv0 + lo5) * HD + kd * 16 + hi * 8);
            st = MFMA32(kf, qf[kd], st);
        }
        if (t == qtile) {   // diagonal tile: causal mask (kv_local > lo5)
#pragma unroll
            for (int r = 0; r < 16; ++r) {
                int kvloc = (r & 3) + 8 * (r >> 2) + 4 * hi;
                st[r] = (kvloc > lo5) ? -INFINITY : st[r];
            }
        }
        float tm = st[0];
#pragma unroll
        for (int r = 1; r < 16; ++r) tm = fmaxf(tm, st[r]);
        tm = fmaxf(tm, __shfl_xor(tm, 32));
        float mnew = fmaxf(m, tm);
        float fac = __expf(m - mnew);

        float p[16];
        float ls = 0.f;
#pragma unroll
        for (int r = 0; r < 16; ++r) {
            p[r] = __expf(st[r] - mnew);
            ls += p[r];
        }
        ls += __shfl_xor(ls, 32);
        lsum = lsum * fac + ls;
#pragma unroll
        for (int r = 0; r < 16; ++r) { o0[r] *= fac; o1[r] *= fac; }
        m = mnew;

        unsigned pk0 = pkbf(p[0],  p[1]),  pk1 = pkbf(p[2],  p[3]);
        unsigned pk2 = pkbf(p[4],  p[5]),  pk3 = pkbf(p[6],  p[7]);
        unsigned pk4 = pkbf(p[8],  p[9]),  pk5 = pkbf(p[10], p[11]);
        unsigned pk6 = pkbf(p[12], p[13]), pk7 = pkbf(p[14], p[15]);
        unsigned r0 = (unsigned)__shfl_xor((int)(hi ? pk0 : pk2), 32);
        unsigned r1 = (unsigned)__shfl_xor((int)(hi ? pk1 : pk3), 32);
        unsigned r2 = (unsigned)__shfl_xor((int)(hi ? pk4 : pk6), 32);
        unsigned r3 = (unsigned)__shfl_xor((int)(hi ? pk5 : pk7), 32);
        bf16x8 pb0 = make_pb(hi ? r0 : pk0, hi ? r1 : pk1,
                             hi ? pk2 : r0, hi ? pk3 : r1);
        bf16x8 pb1 = make_pb(hi ? r2 : pk4, hi ? r3 : pk5,
                             hi ? pk6 : r2, hi ? pk7 : r3);

#pragma unroll
        for (int ks = 0; ks < 2; ++ks) {
            bf16x8 pb = ks ? pb1 : pb0;
            bf16x8 v0 = *reinterpret_cast<const bf16x8*>(
                Vh + (long)(lo5) * SEQ + kv0 + ks * 16 + hi * 8);
            bf16x8 v1 = *reinterpret_cast<const bf16x8*>(
                Vh + (long)(32 + lo5) * SEQ + kv0 + ks * 16 + hi * 8);
            o0 = MFMA32(v0, pb, o0);
            o1 = MFMA32(v1, pb, o1);
        }
    }

    float inv = 1.0f / lsum;
    int b = bh >> 4, h = bh & 15;
    __hip_bfloat16* orow = O + ((long)b * SEQ + q0 + lo5) * DM + h * HD;
#pragma unroll
    for (int nd = 0; nd < 2; ++nd) {
#pragma unroll
        for (int rg = 0; rg < 4; ++rg) {
            ushort4 s4;
            float a0 = (nd ? o1[rg * 4 + 0] : o0[rg * 4 + 0]) * inv;
            float a1 = (nd ? o1[rg * 4 + 1] : o0[rg * 4 + 1]) * inv;
            float a2 = (nd ? o1[rg * 4 + 2] : o0[rg * 4 + 2]) * inv;
            float a3 = (nd ? o1[rg * 4 + 3] : o0[rg * 4 + 3]) * inv;
            s4.x = __bfloat16_as_ushort(__float2bfloat16(a0));
            s4.y = __bfloat16_as_ushort(__float2bfloat16(a1));
            s4.z = __bfloat16_as_ushort(__float2bfloat16(a2));
            s4.w = __bfloat16_as_ushort(__float2bfloat16(a3));
            *reinterpret_cast<ushort4*>(orow + nd * 32 + rg * 8 + hi * 4) = s4;
        }
    }
}

extern "C" void kernel_launch(void* const* d_in, const int* in_sizes, int n_in,
                              void* d_out, int out_size, void* d_ws, size_t ws_size,
                              hipStream_t stream) {
    const float* x  = (const float*)d_in[0];
    const float* Wq = (const float*)d_in[1];
    const float* bq = (const float*)d_in[2];
    const float* Wk = (const float*)d_in[3];
    const float* bk = (const float*)d_in[4];
    const float* Wv = (const float*)d_in[5];
    const float* bv = (const float*)d_in[6];
    const float* Wp = (const float*)d_in[7];
    const float* bp = (const float*)d_in[8];
    float* out = (float*)d_out;

    char* ws = (char*)d_ws;
    const long XE = (long)NB * SEQ * DM;                 // 8,388,608
    const long QKV_ELEMS = (long)NB * NH * SEQ * HD;     // 8,388,608
    __hip_bfloat16* xb   = (__hip_bfloat16*)ws; ws += XE * 2;
    __hip_bfloat16* Qws  = (__hip_bfloat16*)ws; ws += QKV_ELEMS * 2;
    __hip_bfloat16* Kws  = (__hip_bfloat16*)ws; ws += QKV_ELEMS * 2;
    __hip_bfloat16* Vtws = (__hip_bfloat16*)ws; ws += QKV_ELEMS * 2;
    __hip_bfloat16* Ows  = (__hip_bfloat16*)ws; ws += QKV_ELEMS * 2;
    // fused WT[3072][1024]: rows 0-1023 = Wq^T, 1024-2047 = Wk^T, 2048-3071 = Wv^T
    __hip_bfloat16* wqt  = (__hip_bfloat16*)ws; ws += (long)NH * DM * HD * 2;
    __hip_bfloat16* wkt  = (__hip_bfloat16*)ws; ws += (long)NH * DM * HD * 2;
    __hip_bfloat16* wvt  = (__hip_bfloat16*)ws; ws += (long)NH * DM * HD * 2;
    __hip_bfloat16* wpt  = (__hip_bfloat16*)ws; ws += (long)DM * DM * 2;

    cast_f32_bf16<<<(int)(XE / 4 / 256), 256, 0, stream>>>(x, xb, XE);

    {
        long tot = (long)NH * DM * HD;
        int blks = (int)((tot + 255) / 256);
        transpose_cast_k<<<blks, 256, 0, stream>>>(Wq, wqt, NH, DM, HD);
        transpose_cast_k<<<blks, 256, 0, stream>>>(Wk, wkt, NH, DM, HD);
        transpose_cast_k<<<blks, 256, 0, stream>>>(Wv, wvt, NH, DM, HD);
        long tot2 = (long)DM * DM;
        transpose_cast_k<<<(int)((tot2 + 255) / 256), 256, 0, stream>>>(Wp, wpt, 1, DM, DM);
    }

    gemm_bt<0><<<dim3(64, 24), 256, 0, stream>>>(
        xb, wqt, bq, bk, bv, Qws, Kws, Vtws, nullptr);

    flash_attn<<<dim3(16, 64), 256, 0, stream>>>(Qws, Kws, Vtws, Ows);

    gemm_bt<1><<<dim3(64, 8), 256, 0, stream>>>(
        Ows, wpt, bp, nullptr, nullptr, nullptr, nullptr, nullptr, out);
}

// Round 5
// 253.769 us; speedup vs baseline: 4.2064x; 1.5773x over previous
//
#include <hip/hip_runtime.h>
#include <hip/hip_bf16.h>

typedef __attribute__((ext_vector_type(8)))  short bf16x8;
typedef __attribute__((ext_vector_type(4)))  float f32x4;
typedef __attribute__((ext_vector_type(16))) float f32x16;

#define NH  16
#define HD  64
#define SEQ 2048
#define DM  1024   // NH*HD
#define NB  4

// Q pre-scale: 1/sqrt(64) * log2(e)  (softmax done in exp2 domain)
#define QSCALE 0.18033688011112042f

#define MFMA(a,b,c)   __builtin_amdgcn_mfma_f32_16x16x32_bf16((a),(b),(c),0,0,0)
#define MFMA32(a,b,c) __builtin_amdgcn_mfma_f32_32x32x16_bf16((a),(b),(c),0,0,0)

static __device__ __forceinline__ void gload_lds16(const void* g, void* l) {
    __builtin_amdgcn_global_load_lds(
        (const __attribute__((address_space(1))) void*)g,
        (__attribute__((address_space(3))) void*)l, 16, 0, 0);
}

// ---------------- cast float -> bf16, 4 elems/thread ----------------
__global__ void cast_f32_bf16(const float* __restrict__ src,
                              __hip_bfloat16* __restrict__ dst, long n) {
    long i = ((long)blockIdx.x * blockDim.x + threadIdx.x) * 4;
    if (i >= n) return;
    float4 v = *reinterpret_cast<const float4*>(src + i);
    ushort4 o;
    o.x = __bfloat16_as_ushort(__float2bfloat16(v.x));
    o.y = __bfloat16_as_ushort(__float2bfloat16(v.y));
    o.z = __bfloat16_as_ushort(__float2bfloat16(v.z));
    o.w = __bfloat16_as_ushort(__float2bfloat16(v.w));
    *reinterpret_cast<ushort4*>(dst + i) = o;
}

// ------------- transpose+cast [mats][R][C] f32 -> [mats][C][R] bf16 -------------
__global__ void transpose_cast_k(const float* __restrict__ src,
                                 __hip_bfloat16* __restrict__ dst,
                                 int mats, int R, int C) {
    long idx = (long)blockIdx.x * blockDim.x + threadIdx.x;
    long total = (long)mats * R * C;
    if (idx >= total) return;
    int c = (int)(idx % C);
    long t = idx / C;
    int r = (int)(t % R);
    int m = (int)(t / R);
    dst[((long)m * C + c) * R + r] = __float2bfloat16(src[idx]);
}

// ---------------- tiled GEMM: C[M][N] = A[M][1024] * BT[N][1024]^T ----------------
// 128x128 tile, BK=32, double-buffered LDS via global_load_lds(16B), XOR swizzle.
// MODE 0: qkv epilogue (N=3072 fused; z selects Q/K/V layout+bias, Q*=QSCALE)
// MODE 1: float-out epilogue with bias (out projection)
template<int MODE>
__global__ __launch_bounds__(256)
void gemm_bt(const __hip_bfloat16* __restrict__ A,
             const __hip_bfloat16* __restrict__ BT,
             const float* __restrict__ b0,
             const float* __restrict__ b1,
             const float* __restrict__ b2,
             __hip_bfloat16* __restrict__ Qo,
             __hip_bfloat16* __restrict__ Ko,
             __hip_bfloat16* __restrict__ Vto,
             float* __restrict__ Fo) {
    __shared__ __align__(16) char smem[2][16384];   // [buf][A:0..8191 | B:8192..16383]
    int tid = threadIdx.x;
    int w = tid >> 6, l = tid & 63;
    int wr = w >> 1, wc = w & 1;
    int lr = l & 15, lg = l >> 4;
    int mtile = blockIdx.x, ntile = blockIdx.y;

    const __hip_bfloat16* Ab = A  + (long)mtile * 128 * DM;
    const __hip_bfloat16* Bb = BT + (long)ntile * 128 * DM;

    const int srow0 = tid >> 2;
    const int srow1 = 64 + srow0;
    const int g0 = (tid & 3) ^ ((srow0 >> 1) & 3);

    int aoff[4], boff[4];
#pragma unroll
    for (int m = 0; m < 4; ++m) {
        int ra = wr * 64 + m * 16 + lr;
        aoff[m] = ra * 64 + ((lg ^ ((ra >> 1) & 3)) * 16);
        int rb = wc * 64 + m * 16 + lr;
        boff[m] = 8192 + rb * 64 + ((lg ^ ((rb >> 1) & 3)) * 16);
    }

    f32x4 acc[4][4] = {};

    {
        char* base = smem[0] + w * 1024;
        gload_lds16(Ab + (long)srow0 * DM + g0 * 8, base);
        gload_lds16(Ab + (long)srow1 * DM + g0 * 8, base + 4096);
        gload_lds16(Bb + (long)srow0 * DM + g0 * 8, base + 8192);
        gload_lds16(Bb + (long)srow1 * DM + g0 * 8, base + 12288);
    }
    __syncthreads();

    int cur = 0;
    for (int kt = 0; kt < 32; ++kt) {
        if (kt != 31) {
            int k0 = (kt + 1) * 32;
            char* base = smem[cur ^ 1] + w * 1024;
            gload_lds16(Ab + (long)srow0 * DM + k0 + g0 * 8, base);
            gload_lds16(Ab + (long)srow1 * DM + k0 + g0 * 8, base + 4096);
            gload_lds16(Bb + (long)srow0 * DM + k0 + g0 * 8, base + 8192);
            gload_lds16(Bb + (long)srow1 * DM + k0 + g0 * 8, base + 12288);
        }
        bf16x8 af[4], bf[4];
#pragma unroll
        for (int m = 0; m < 4; ++m)
            af[m] = *reinterpret_cast<const bf16x8*>(smem[cur] + aoff[m]);
#pragma unroll
        for (int n = 0; n < 4; ++n)
            bf[n] = *reinterpret_cast<const bf16x8*>(smem[cur] + boff[n]);
#pragma unroll
        for (int m = 0; m < 4; ++m)
#pragma unroll
            for (int n = 0; n < 4; ++n)
                acc[m][n] = MFMA(af[m], bf[n], acc[m][n]);
        __syncthreads();
        cur ^= 1;
    }

    if (MODE == 0) {
        int z = (ntile * 128) >> 10;
        const float* bias = (z == 0) ? b0 : (z == 1) ? b1 : b2;
        int colbase = (ntile * 128 + wc * 64) & 1023;
#pragma unroll
        for (int n = 0; n < 4; ++n) {
            int hc = colbase + n * 16 + lr;               // h*64+e
            int h = hc >> 6, e = hc & 63;
            float bb = bias[hc];
#pragma unroll
            for (int m = 0; m < 4; ++m) {
                int row0 = mtile * 128 + wr * 64 + m * 16 + lg * 4;
                int b = row0 >> 11, s0 = row0 & 2047;
                if (z == 0) {
#pragma unroll
                    for (int r = 0; r < 4; ++r)
                        Qo[(((long)b * NH + h) * SEQ + s0 + r) * HD + e] =
                            __float2bfloat16((acc[m][n][r] + bb) * QSCALE);
                } else if (z == 1) {
#pragma unroll
                    for (int r = 0; r < 4; ++r)
                        Ko[(((long)b * NH + h) * SEQ + s0 + r) * HD + e] =
                            __float2bfloat16(acc[m][n][r] + bb);
                } else {
                    ushort4 s4;
                    s4.x = __bfloat16_as_ushort(__float2bfloat16(acc[m][n][0] + bb));
                    s4.y = __bfloat16_as_ushort(__float2bfloat16(acc[m][n][1] + bb));
                    s4.z = __bfloat16_as_ushort(__float2bfloat16(acc[m][n][2] + bb));
                    s4.w = __bfloat16_as_ushort(__float2bfloat16(acc[m][n][3] + bb));
                    *reinterpret_cast<ushort4*>(
                        Vto + ((long)(b * NH + h) * HD + e) * SEQ + s0) = s4;
                }
            }
        }
    } else {
#pragma unroll
        for (int n = 0; n < 4; ++n) {
            int col = ntile * 128 + wc * 64 + n * 16 + lr;
            float bb = b0[col];
#pragma unroll
            for (int m = 0; m < 4; ++m) {
                long row0 = mtile * 128 + wr * 64 + m * 16 + lg * 4;
#pragma unroll
                for (int r = 0; r < 4; ++r)
                    Fo[(row0 + r) * DM + col] = acc[m][n][r] + bb;
            }
        }
    }
}

// ---------------- helpers for flash ----------------
static __device__ __forceinline__ unsigned pkbf(float a, float b) {
    __hip_bfloat162 h = __float22bfloat162_rn(float2{a, b});  // a -> low 16
    union { __hip_bfloat162 h2; unsigned u; } u_; u_.h2 = h;
    return u_.u;
}
static __device__ __forceinline__ bf16x8 make_pb(unsigned w0, unsigned w1,
                                                 unsigned w2, unsigned w3) {
    union { unsigned u[4]; bf16x8 v; } u_;
    u_.u[0] = w0; u_.u[1] = w1; u_.u[2] = w2; u_.u[3] = w3;
    return u_.v;
}

// One kv-tile of one chain: QK^T (swapped), online softmax (exp2 domain,
// defer-max), P->bf16 B-frags, PV accumulate.
template<bool MASKED>
static __device__ __forceinline__ void attn_tile(
    const bf16x8* kf, const bf16x8* qf,
    bf16x8 v00, bf16x8 v10, bf16x8 v01, bf16x8 v11,
    int lo5, int hi,
    f32x16& o0, f32x16& o1, float& m, float& lsum) {
    f32x16 st = {};
#pragma unroll
    for (int kd = 0; kd < 4; ++kd) st = MFMA32(kf[kd], qf[kd], st);
    if (MASKED) {
#pragma unroll
        for (int r = 0; r < 16; ++r) {
            int kvloc = (r & 3) + 8 * (r >> 2) + 4 * hi;
            st[r] = (kvloc > lo5) ? -INFINITY : st[r];
        }
    }
    float tm = st[0];
#pragma unroll
    for (int r = 1; r < 16; ++r) tm = fmaxf(tm, st[r]);
    tm = fmaxf(tm, __shfl_xor(tm, 32));
    if (!__all(tm <= m + 11.0f)) {          // defer-max: p bounded by 2^11
        float mnew = fmaxf(m, tm);
        float fac = exp2f(m - mnew);
        lsum *= fac;
#pragma unroll
        for (int r = 0; r < 16; ++r) { o0[r] *= fac; o1[r] *= fac; }
        m = mnew;
    }
    float p[16], ls = 0.f;
#pragma unroll
    for (int r = 0; r < 16; ++r) { p[r] = exp2f(st[r] - m); ls += p[r]; }
    ls += __shfl_xor(ls, 32);
    lsum += ls;

    unsigned pk0 = pkbf(p[0],  p[1]),  pk1 = pkbf(p[2],  p[3]);
    unsigned pk2 = pkbf(p[4],  p[5]),  pk3 = pkbf(p[6],  p[7]);
    unsigned pk4 = pkbf(p[8],  p[9]),  pk5 = pkbf(p[10], p[11]);
    unsigned pk6 = pkbf(p[12], p[13]), pk7 = pkbf(p[14], p[15]);
    unsigned r0 = (unsigned)__shfl_xor((int)(hi ? pk0 : pk2), 32);
    unsigned r1 = (unsigned)__shfl_xor((int)(hi ? pk1 : pk3), 32);
    unsigned r2 = (unsigned)__shfl_xor((int)(hi ? pk4 : pk6), 32);
    unsigned r3 = (unsigned)__shfl_xor((int)(hi ? pk5 : pk7), 32);
    bf16x8 pb0 = make_pb(hi ? r0 : pk0, hi ? r1 : pk1,
                         hi ? pk2 : r0, hi ? pk3 : r1);
    bf16x8 pb1 = make_pb(hi ? r2 : pk4, hi ? r3 : pk5,
                         hi ? pk6 : r2, hi ? pk7 : r3);

    o0 = MFMA32(v00, pb0, o0);
    o1 = MFMA32(v10, pb0, o1);
    o0 = MFMA32(v01, pb1, o0);
    o1 = MFMA32(v11, pb1, o1);
}

// ---------------- flash attention (causal, paired antidiagonal waves) ----------------
// Q (pre-scaled by QSCALE), K: [B,H,S,HD]; Vt: [B,H,HD,S]; O: [B*S][DM] (col h*64+d)
// Wave handles q-tiles jA=pair and jB=63-pair: 65 tile-computes each (balanced),
// shared K/V loads, 2 independent chains for ILP, K prefetched one tile ahead.
__global__ __launch_bounds__(256)
void flash_attn(const __hip_bfloat16* __restrict__ Q,
                const __hip_bfloat16* __restrict__ K,
                const __hip_bfloat16* __restrict__ Vt,
                __hip_bfloat16* __restrict__ O) {
    int bh = blockIdx.x;                       // x=bh: same-head blocks share XCD
    int w  = threadIdx.x >> 6, l = threadIdx.x & 63;
    int lo5 = l & 31, hi = l >> 5;
    int pair = blockIdx.y * 4 + w;             // 0..31
    int jA = pair, jB = 63 - pair;
    int q0A = jA * 32, q0B = jB * 32;

    const __hip_bfloat16* Qh = Q  + (long)bh * SEQ * HD;
    const __hip_bfloat16* Kh = K  + (long)bh * SEQ * HD;
    const __hip_bfloat16* Vh = Vt + (long)bh * HD * SEQ;   // [64][2048]

    bf16x8 qfA[4], qfB[4];
#pragma unroll
    for (int kd = 0; kd < 4; ++kd) {
        qfA[kd] = *reinterpret_cast<const bf16x8*>(
            Qh + (long)(q0A + lo5) * HD + kd * 16 + hi * 8);
        qfB[kd] = *reinterpret_cast<const bf16x8*>(
            Qh + (long)(q0B + lo5) * HD + kd * 16 + hi * 8);
    }

    f32x16 oA0 = {}, oA1 = {}, oB0 = {}, oB1 = {};
    float mA = -INFINITY, lsA = 0.f, mB = -INFINITY, lsB = 0.f;

    bf16x8 kf[4], kn[4];
#pragma unroll
    for (int kd = 0; kd < 4; ++kd)
        kf[kd] = *reinterpret_cast<const bf16x8*>(
            Kh + (long)(lo5) * HD + kd * 16 + hi * 8);

#define LOADK(T, DST)                                                      \
    _Pragma("unroll")                                                      \
    for (int kd = 0; kd < 4; ++kd)                                         \
        DST[kd] = *reinterpret_cast<const bf16x8*>(                        \
            Kh + (long)((T) * 32 + lo5) * HD + kd * 16 + hi * 8);

#define LOADV(KV0)                                                         \
    bf16x8 v00 = *reinterpret_cast<const bf16x8*>(                         \
        Vh + (long)(lo5) * SEQ + (KV0) + hi * 8);                          \
    bf16x8 v10 = *reinterpret_cast<const bf16x8*>(                         \
        Vh + (long)(32 + lo5) * SEQ + (KV0) + hi * 8);                     \
    bf16x8 v01 = *reinterpret_cast<const bf16x8*>(                         \
        Vh + (long)(lo5) * SEQ + (KV0) + 16 + hi * 8);                     \
    bf16x8 v11 = *reinterpret_cast<const bf16x8*>(                         \
        Vh + (long)(32 + lo5) * SEQ + (KV0) + 16 + hi * 8);

    for (int t = 0; t < jA; ++t) {
        LOADK(t + 1, kn);
        LOADV(t * 32);
        attn_tile<false>(kf, qfB, v00, v10, v01, v11, lo5, hi, oB0, oB1, mB, lsB);
        attn_tile<false>(kf, qfA, v00, v10, v01, v11, lo5, hi, oA0, oA1, mA, lsA);
        kf[0] = kn[0]; kf[1] = kn[1]; kf[2] = kn[2]; kf[3] = kn[3];
    }
    {   // t = jA: A's diagonal
        LOADK(jA + 1, kn);
        LOADV(jA * 32);
        attn_tile<true >(kf, qfA, v00, v10, v01, v11, lo5, hi, oA0, oA1, mA, lsA);
        attn_tile<false>(kf, qfB, v00, v10, v01, v11, lo5, hi, oB0, oB1, mB, lsB);
        kf[0] = kn[0]; kf[1] = kn[1]; kf[2] = kn[2]; kf[3] = kn[3];
    }
    for (int t = jA + 1; t < jB; ++t) {
        LOADK(t + 1, kn);
        LOADV(t * 32);
        attn_tile<false>(kf, qfB, v00, v10, v01, v11, lo5, hi, oB0, oB1, mB, lsB);
        kf[0] = kn[0]; kf[1] = kn[1]; kf[2] = kn[2]; kf[3] = kn[3];
    }
    {   // t = jB: B's diagonal
        LOADV(jB * 32);
        attn_tile<true >(kf, qfB, v00, v10, v01, v11, lo5, hi, oB0, oB1, mB, lsB);
    }
#undef LOADK
#undef LOADV

    int b = bh >> 4, h = bh & 15;
#pragma unroll
    for (int c = 0; c < 2; ++c) {
        int q0 = c ? q0B : q0A;
        const f32x16& o0 = c ? oB0 : oA0;
        const f32x16& o1 = c ? oB1 : oA1;
        float inv = 1.0f / (c ? lsB : lsA);
        __hip_bfloat16* orow = O + ((long)b * SEQ + q0 + lo5) * DM + h * HD;
#pragma unroll
        for (int nd = 0; nd < 2; ++nd) {
#pragma unroll
            for (int rg = 0; rg < 4; ++rg) {
                ushort4 s4;
                float a0 = (nd ? o1[rg * 4 + 0] : o0[rg * 4 + 0]) * inv;
                float a1 = (nd ? o1[rg * 4 + 1] : o0[rg * 4 + 1]) * inv;
                float a2 = (nd ? o1[rg * 4 + 2] : o0[rg * 4 + 2]) * inv;
                float a3 = (nd ? o1[rg * 4 + 3] : o0[rg * 4 + 3]) * inv;
                s4.x = __bfloat16_as_ushort(__float2bfloat16(a0));
                s4.y = __bfloat16_as_ushort(__float2bfloat16(a1));
                s4.z = __bfloat16_as_ushort(__float2bfloat16(a2));
                s4.w = __bfloat16_as_ushort(__float2bfloat16(a3));
                *reinterpret_cast<ushort4*>(orow + nd * 32 + rg * 8 + hi * 4) = s4;
            }
        }
    }
}

extern "C" void kernel_launch(void* const* d_in, const int* in_sizes, int n_in,
                              void* d_out, int out_size, void* d_ws, size_t ws_size,
                              hipStream_t stream) {
    const float* x  = (const float*)d_in[0];
    const float* Wq = (const float*)d_in[1];
    const float* bq = (const float*)d_in[2];
    const float* Wk = (const float*)d_in[3];
    const float* bk = (const float*)d_in[4];
    const float* Wv = (const float*)d_in[5];
    const float* bv = (const float*)d_in[6];
    const float* Wp = (const float*)d_in[7];
    const float* bp = (const float*)d_in[8];
    float* out = (float*)d_out;

    char* ws = (char*)d_ws;
    const long XE = (long)NB * SEQ * DM;                 // 8,388,608
    const long QKV_ELEMS = (long)NB * NH * SEQ * HD;     // 8,388,608
    __hip_bfloat16* xb   = (__hip_bfloat16*)ws; ws += XE * 2;
    __hip_bfloat16* Qws  = (__hip_bfloat16*)ws; ws += QKV_ELEMS * 2;
    __hip_bfloat16* Kws  = (__hip_bfloat16*)ws; ws += QKV_ELEMS * 2;
    __hip_bfloat16* Vtws = (__hip_bfloat16*)ws; ws += QKV_ELEMS * 2;
    __hip_bfloat16* Ows  = (__hip_bfloat16*)ws; ws += QKV_ELEMS * 2;
    // fused WT[3072][1024]: rows 0-1023 = Wq^T, 1024-2047 = Wk^T, 2048-3071 = Wv^T
    __hip_bfloat16* wqt  = (__hip_bfloat16*)ws; ws += (long)NH * DM * HD * 2;
    __hip_bfloat16* wkt  = (__hip_bfloat16*)ws; ws += (long)NH * DM * HD * 2;
    __hip_bfloat16* wvt  = (__hip_bfloat16*)ws; ws += (long)NH * DM * HD * 2;
    __hip_bfloat16* wpt  = (__hip_bfloat16*)ws; ws += (long)DM * DM * 2;

    cast_f32_bf16<<<(int)(XE / 4 / 256), 256, 0, stream>>>(x, xb, XE);

    {
        long tot = (long)NH * DM * HD;
        int blks = (int)((tot + 255) / 256);
        transpose_cast_k<<<blks, 256, 0, stream>>>(Wq, wqt, NH, DM, HD);
        transpose_cast_k<<<blks, 256, 0, stream>>>(Wk, wkt, NH, DM, HD);
        transpose_cast_k<<<blks, 256, 0, stream>>>(Wv, wvt, NH, DM, HD);
        long tot2 = (long)DM * DM;
        transpose_cast_k<<<(int)((tot2 + 255) / 256), 256, 0, stream>>>(Wp, wpt, 1, DM, DM);
    }

    gemm_bt<0><<<dim3(64, 24), 256, 0, stream>>>(
        xb, wqt, bq, bk, bv, Qws, Kws, Vtws, nullptr);

    flash_attn<<<dim3(64, 8), 256, 0, stream>>>(Qws, Kws, Vtws, Ows);

    gemm_bt<1><<<dim3(64, 8), 256, 0, stream>>>(
        Ows, wpt, bp, nullptr, nullptr, nullptr, nullptr, nullptr, out);
}